// Round 14
// baseline (71.524 us; speedup 1.0000x reference)
//
#include <hip/hip_runtime.h>

// AdaptiveConv: out[b,c,h,w] = sum_{idx<25} x[b,c,h+idx/5, w+idx%5] * kernel[b,idx,h,w]
// Shapes: x (8,64,260,260) f32, kernel (8,25,256,256) f32, out (8,64,256,256) f32.
//
// R13: R9->R11 showed neither occupancy (20->42%: flat) nor tap prefetch (flat)
// moves the 65us plateau. Budget: staging-serial (~15us) + compute (~50us) = 65
// => phase-locked convoy: all blocks stage, barrier, compute in lockstep.
// Fix: intra-block pipeline. Each block runs 4 channel-groups with ping-pong
// LDS buffers: stage(g+1) issued BEFORE compute(g) -> staging hidden for 3 of
// 4 phases. Staging via global_load_lds width=16 (no VGPR round-trip, no
// ds_write issue). Channel slice padded 2080->2304 floats = 9 exact full-wave
// sweeps (pad never read; last-plane OOB clamped). Inner loop frozen from R10.

constexpr int K  = 5;
constexpr int B  = 8;
constexpr int C  = 64;
constexpr int H  = 256;
constexpr int W  = 256;
constexpr int HX = H + K - 1;   // 260
constexpr int WX = W + K - 1;   // 260

constexpr int CH  = 4;          // channels per acc block (tap amortization /4)
constexpr int NCG = C / CH;     // 16 channel groups
constexpr int GPB = 4;          // channel groups per block (ping-pong depth)
constexpr int CGB = NCG / GPB;  // 4 group-slots in grid
constexpr int HPB = 4;          // output rows per block (one per wave)
constexpr int NHB = H / HPB;    // 64 h-blocks
constexpr int NWG = NHB * B * CGB;  // 2048 blocks

constexpr int CH_REAL = (HPB + K - 1) * WX;  // 2080 floats actually used
constexpr int CH_PAD  = 2304;                // 9 sweeps x 256 floats (gll-exact)
constexpr int BUF_FLOATS = CH * CH_PAD;      // 9216 floats = 36,864 B per buffer

typedef float f4 __attribute__((ext_vector_type(4)));

__global__ __launch_bounds__(256, 2)
void adaptive_conv_kernel(const float* __restrict__ x,
                          const float* __restrict__ kern,
                          float* __restrict__ out) {
    __shared__ float xs[2][BUF_FLOATS];      // 73,728 B total -> 2 blocks/CU

    // XCD-aware swizzle (bijective: NWG % 8 == 0); group-slot fastest so blocks
    // sharing one kern tile run consecutively on one XCD (R8, FETCH-verified).
    const int k    = blockIdx.x;
    const int orig = (k & 7) * (NWG / 8) + (k >> 3);
    const int cgs  = orig & (CGB - 1);          // group-slot (fastest)
    const int hblk = (orig >> 2) & (NHB - 1);   // h-block
    const int b    = orig >> 8;                 // batch (slowest)

    const int tid  = threadIdx.x;
    const int lane = tid & 63;               // lane within wave
    const int wv   = tid >> 6;               // 0..3: wave id = row slice
    const int w0   = lane * 4;               // 4 adjacent output columns
    const int h    = hblk * HPB + wv;        // output row

    const size_t xplane = (size_t)HX * WX;
    const size_t XTOT   = (size_t)B * C * xplane;
    const float* kb = kern + (size_t)b * (K * K * H * W) + (size_t)h * W + w0;

    // Stage channel (group t)'s wave-owned plane slice into buffer p.
    // 9 full-wave global_load_lds sweeps of 1024B: LDS dst = uniform base +
    // lane*16 (linear, matches layout); global src per-lane, 16B-aligned.
    // Sweep 8 (floats 2048..2303) covers the 2048..2079 tail actually used
    // (always in-plane) plus pad; clamp the rare last-plane overrun.
    auto stage = [&](int t, int p) {
        const int ch = (cgs * GPB + t) * CH + wv;
        const float* src = x + ((size_t)b * C + ch) * xplane
                             + (size_t)(hblk * HPB) * WX;
        #pragma unroll
        for (int s = 0; s < 9; ++s) {
            const float* gp = src + s * 256 + lane * 4;
            if (s == 8 && gp + 4 > x + XTOT) gp = x;   // pad region, data unused
            float* lp = &xs[p][wv * CH_PAD + s * 256];  // wave-uniform base
            __builtin_amdgcn_global_load_lds(
                (const __attribute__((address_space(1))) void*)gp,
                (__attribute__((address_space(3))) void*)lp, 16, 0, 0);
        }
    };

    stage(0, 0);            // prologue: only exposed stage (1 of 4)
    __syncthreads();        // drains vmcnt -> buffer 0 ready

    #pragma unroll
    for (int t = 0; t < GPB; ++t) {
        const int p = t & 1;
        if (t + 1 < GPB) stage(t + 1, p ^ 1);   // overlaps compute below

        const int c0 = (cgs * GPB + t) * CH;

        f4 acc[CH];
        #pragma unroll
        for (int ch = 0; ch < CH; ++ch) acc[ch] = (f4)0.0f;

        #pragma unroll
        for (int i = 0; i < K; ++i) {
            // Tap row i: 5 float4, reused across 4 channels; L2-resident via
            // the swizzle (kern is channel-independent).
            f4 tc[K];
            #pragma unroll
            for (int j = 0; j < K; ++j) {
                tc[j] = *(const f4*)(kb + (size_t)(i * K + j) * (H * W));
            }

            #pragma unroll
            for (int ch = 0; ch < CH; ++ch) {
                // x row (wv+i), cols w0..w0+7 from LDS: lane*16B sequential,
                // conflict-free (2-way aliasing is free).
                const float* xr = &xs[p][ch * CH_PAD + (wv + i) * WX + w0];
                f4 xa  = *(const f4*)(xr);
                f4 xcv = *(const f4*)(xr + 4);
                float xsg[8] = {xa.x, xa.y, xa.z, xa.w, xcv.x, xcv.y, xcv.z, xcv.w};

                #pragma unroll
                for (int j = 0; j < K; ++j) {      // static indices only
                    acc[ch].x = fmaf(xsg[j + 0], tc[j].x, acc[ch].x);
                    acc[ch].y = fmaf(xsg[j + 1], tc[j].y, acc[ch].y);
                    acc[ch].z = fmaf(xsg[j + 2], tc[j].z, acc[ch].z);
                    acc[ch].w = fmaf(xsg[j + 3], tc[j].w, acc[ch].w);
                }
            }
        }

        float* ob = out + ((size_t)b * C + c0) * (H * W) + (size_t)h * W + w0;
        #pragma unroll
        for (int ch = 0; ch < CH; ++ch) {
            // out written once, never read: bypass caches.
            __builtin_nontemporal_store(acc[ch], (f4*)(ob + (size_t)ch * (H * W)));
        }

        if (t + 1 < GPB) __syncthreads();   // next buffer ready; no WAR hazard
    }
}

extern "C" void kernel_launch(void* const* d_in, const int* in_sizes, int n_in,
                              void* d_out, int out_size, void* d_ws, size_t ws_size,
                              hipStream_t stream) {
    const float* x    = (const float*)d_in[0];
    const float* kern = (const float*)d_in[1];
    float*       out  = (float*)d_out;

    dim3 grid(NWG);      // 2048 blocks, 1D; decode + swizzle in-kernel
    dim3 block(256);     // 4 row-slices x 64 lanes
    adaptive_conv_kernel<<<grid, block, 0, stream>>>(x, kern, out);
}

// Round 15
// 65.742 us; speedup vs baseline: 1.0879x; 1.0879x over previous
//
#include <hip/hip_runtime.h>

// AdaptiveConv: out[b,c,h,w] = sum_{idx<25} x[b,c,h+idx/5, w+idx%5] * kernel[b,idx,h,w]
// Shapes: x (8,64,260,260) f32, kernel (8,25,256,256) f32, out (8,64,256,256) f32.
//
// R14: R13 (intra-block ping-pong, 2 blk/CU) regressed -> staging overlap gains
// ~0; convoy theory dead; reverted. Re-audit of R11: launch_bounds(256,4) made
// the allocator pick VGPR=64 (aiming for 8 waves/SIMD that LDS already forbids),
// leaving no room for the tap prefetch -> it was sunk, the experiment never ran.
// R13 proved the allocator goes to 128 under (256,2). With 33.3KB LDS, VGPR<=128
// still allows 4 blocks/CU = 16 waves/CU, so relaxing the bound is free.
// R14 = R11 body EXACTLY, one change: __launch_bounds__(256,2).
// Signature to check: VGPR 64 -> 96..128 means the prefetch survived.

constexpr int K  = 5;
constexpr int B  = 8;
constexpr int C  = 64;
constexpr int H  = 256;
constexpr int W  = 256;
constexpr int HX = H + K - 1;   // 260
constexpr int WX = W + K - 1;   // 260

constexpr int CH  = 4;          // channels per thread (acc blocking)
constexpr int NCG = C / CH;     // 16 channel groups
constexpr int HPB = 4;          // output rows per block (one per 64-lane slice)
constexpr int NHB = H / HPB;    // 64 h-blocks
constexpr int NWG = NHB * B * NCG;  // 8192 blocks

constexpr int XROWS      = HPB + K - 1;      // 8 x-rows per block
constexpr int CH_FLOATS  = XROWS * WX;       // 2080 floats per channel
constexpr int LDS_FLOATS = CH * CH_FLOATS;   // 8320 floats = 33,280 B

typedef float f4 __attribute__((ext_vector_type(4)));

__global__ __launch_bounds__(256, 2)
void adaptive_conv_kernel(const float* __restrict__ x,
                          const float* __restrict__ kern,
                          float* __restrict__ out) {
    __shared__ float xs[LDS_FLOATS];

    // XCD-aware swizzle (bijective: NWG % 8 == 0); cg fastest so the 16 blocks
    // sharing one kern tile run consecutively on one XCD (R8, FETCH-verified).
    const int k    = blockIdx.x;
    const int orig = (k & 7) * (NWG / 8) + (k >> 3);
    const int cg   = orig & (NCG - 1);          // channel group (fastest)
    const int hblk = (orig >> 4) & (NHB - 1);   // h-block
    const int b    = orig >> 10;                // batch (slowest)

    const int tid  = threadIdx.x;
    const int lane = tid & 63;               // lane within wave; wave spans full W
    const int wv   = tid >> 6;               // 0..3: wave id = row slice
    const int w0   = lane * 4;               // 4 adjacent output columns (16B aligned)
    const int h    = hblk * HPB + wv;        // output row
    const int c0   = cg * CH;                // channel base

    const size_t xplane = (size_t)HX * WX;
    const float* kb = kern + (size_t)b * (K * K * H * W) + (size_t)h * W + w0;

    // ---- stage x[b, c0:c0+4, h0:h0+8, 0:260] -> LDS (33.3 KB, once) ----
    // Wave wv stages channel wv: 8 full-wave f4 sweeps + an 8-lane tail.
    {
        const float* src = x + ((size_t)b * C + c0 + wv) * xplane
                             + (size_t)(hblk * HPB) * WX;
        float* dst = &xs[wv * CH_FLOATS];
        #pragma unroll
        for (int t = 0; t < 8; ++t) {
            f4 v = *(const f4*)(src + t * 256 + lane * 4);
            *(f4*)(dst + t * 256 + lane * 4) = v;
        }
        if (lane < 8) {
            f4 v = *(const f4*)(src + 2048 + lane * 4);
            *(f4*)(dst + 2048 + lane * 4) = v;
        }
    }

    // Tap row 0 prefetch: issued before the barrier so its L2/L3 latency hides
    // under the staging drain (the barrier waits vmcnt(0) anyway).
    f4 tcur[K], tnxt[K];
    #pragma unroll
    for (int j = 0; j < K; ++j) {
        tcur[j] = *(const f4*)(kb + (size_t)j * (H * W));
    }

    __syncthreads();

    f4 acc[CH];
    #pragma unroll
    for (int ch = 0; ch < CH; ++ch) acc[ch] = (f4)0.0f;

    #pragma unroll
    for (int i = 0; i < K; ++i) {
        // Depth-1 pipeline: issue tap row i+1 loads, then compute with row i.
        // ~250+ cyc of FMA+LDS per i covers one L2-hit latency. (256,2) gives
        // the allocator room (<=128 VGPR keeps 4 blocks/CU with 33.3KB LDS).
        if (i + 1 < K) {
            #pragma unroll
            for (int j = 0; j < K; ++j) {
                tnxt[j] = *(const f4*)(kb + (size_t)((i + 1) * K + j) * (H * W));
            }
        }

        #pragma unroll
        for (int ch = 0; ch < CH; ++ch) {
            // x row segment from LDS: cols w0..w0+7 of x-row (wv+i).
            // byte addr = 16*lane + const -> sequential 16B/lane, conflict-free.
            const float* xr = &xs[ch * CH_FLOATS + (wv + i) * WX + w0];
            f4 xa  = *(const f4*)(xr);
            f4 xcv = *(const f4*)(xr + 4);
            float xsg[8] = {xa.x, xa.y, xa.z, xa.w, xcv.x, xcv.y, xcv.z, xcv.w};

            #pragma unroll
            for (int j = 0; j < K; ++j) {      // static indices only (rule #20)
                acc[ch].x = fmaf(xsg[j + 0], tcur[j].x, acc[ch].x);
                acc[ch].y = fmaf(xsg[j + 1], tcur[j].y, acc[ch].y);
                acc[ch].z = fmaf(xsg[j + 2], tcur[j].z, acc[ch].z);
                acc[ch].w = fmaf(xsg[j + 3], tcur[j].w, acc[ch].w);
            }
        }

        if (i + 1 < K) {
            #pragma unroll
            for (int j = 0; j < K; ++j) tcur[j] = tnxt[j];   // renamed away by RA
        }
    }

    float* ob = out + ((size_t)b * C + c0) * (H * W) + (size_t)h * W + w0;
    #pragma unroll
    for (int ch = 0; ch < CH; ++ch) {
        // out written once, never read: bypass caches (keeps x+kern L3-resident).
        __builtin_nontemporal_store(acc[ch], (f4*)(ob + (size_t)ch * (H * W)));
    }
}

extern "C" void kernel_launch(void* const* d_in, const int* in_sizes, int n_in,
                              void* d_out, int out_size, void* d_ws, size_t ws_size,
                              hipStream_t stream) {
    const float* x    = (const float*)d_in[0];
    const float* kern = (const float*)d_in[1];
    float*       out  = (float*)d_out;

    dim3 grid(NWG);      // 8192 blocks, 1D; decode + swizzle in-kernel
    dim3 block(256);     // 4 row-slices x 64 lanes
    adaptive_conv_kernel<<<grid, block, 0, stream>>>(x, kern, out);
}